// Round 1
// baseline (40162.491 us; speedup 1.0000x reference)
//
#include <hip/hip_runtime.h>

// LureSystem recurrence, MI355X.
// Strategy: batch-parallel (256 blocks, 1 batch element each, 1 block/CU),
// serial loop over 2048 steps inside the kernel. Big matrices (C2,A,B2) in
// per-thread registers as packed f16 (v_dot2_f32_f16, 2 MAC/cyc/lane);
// small matrices (D21,B,C,D12,D) in LDS transposed-packed; state x,w as f16
// in LDS; fp32 accumulation; e computed fully inline (no workspace).

#define NSTEP 2048

typedef _Float16 half_t;
typedef _Float16 half2_t __attribute__((ext_vector_type(2)));

__device__ __forceinline__ float fdot2(half2_t a, half2_t b, float c) {
    return __builtin_amdgcn_fdot2(a, b, c, false);
}

union F4H { float4 f; half2_t h[4]; };
union F2H { float2 f; half2_t h[2]; };

__device__ __forceinline__ float tanh_fast(float p) {
    float ex = __expf(2.0f * p);
    return 1.0f - 2.0f / (ex + 1.0f);
}

// LDS layout (bytes):
//      0: D21T4  [16 j4][256 i][4h]  32768
//  32768: BT4    [16 j4][256 i][4h]  32768
//  65536: CT4    [64 j4][ 64 i][4h]  32768
//  98304: D12T4  [64 j4][ 64 i][4h]  32768
// 131072: DT4    [16 j4][ 64 i][4h]   8192
// 139264: x_h    [256] half            512
// 139776: w_h    [256] half            512
// 140288: d_h    [2][64] half          256
// 140544: red_a  [512] float          2048
// 142592: red_e  [512] float          2048
// total 144640 B
#define LDS_TOTAL 144640

__global__ __launch_bounds__(512, 2)
void lure_kernel(const float* __restrict__ d_g, const float* __restrict__ x0_g,
                 const float* __restrict__ A_g, const float* __restrict__ B_g,
                 const float* __restrict__ B2_g, const float* __restrict__ C_g,
                 const float* __restrict__ D_g, const float* __restrict__ D12_g,
                 const float* __restrict__ C2_g, const float* __restrict__ D21_g,
                 float* __restrict__ out)
{
    extern __shared__ char smem[];
    half_t* D21T = (half_t*)(smem + 0);
    half_t* BT   = (half_t*)(smem + 32768);
    half_t* CT   = (half_t*)(smem + 65536);
    half_t* D12T = (half_t*)(smem + 98304);
    half_t* DT   = (half_t*)(smem + 131072);
    half_t* x_h  = (half_t*)(smem + 139264);
    half_t* w_h  = (half_t*)(smem + 139776);
    half_t* d_h  = (half_t*)(smem + 140288);
    float*  red_a= (float*)(smem + 140544);
    float*  red_e= (float*)(smem + 142592);

    const int t = threadIdx.x;
    const int b = blockIdx.x;
    const int i = t & 255;    // output row for w/x phases
    const int g = t >> 8;     // K-half (0: j 0..127 / d 0..31, 1: rest)
    const int ie = t & 63;    // output row for e phase
    const int sl = t >> 6;    // e-phase K slice (8 slices)

    // ---- one-time: register-resident slices of C2, A, B2 (row i, half g)
    half2_t c2r[64], ar[64], b2r[64];
    {
        const float4* c2p = (const float4*)(C2_g + i * 256 + g * 128);
        const float4* ap  = (const float4*)(A_g  + i * 256 + g * 128);
        const float4* b2p = (const float4*)(B2_g + i * 256 + g * 128);
#pragma unroll
        for (int u = 0; u < 32; ++u) {
            float4 v;
            v = c2p[u];
            c2r[2*u]   = half2_t{(half_t)v.x, (half_t)v.y};
            c2r[2*u+1] = half2_t{(half_t)v.z, (half_t)v.w};
            v = ap[u];
            ar[2*u]    = half2_t{(half_t)v.x, (half_t)v.y};
            ar[2*u+1]  = half2_t{(half_t)v.z, (half_t)v.w};
            v = b2p[u];
            b2r[2*u]   = half2_t{(half_t)v.x, (half_t)v.y};
            b2r[2*u+1] = half2_t{(half_t)v.z, (half_t)v.w};
        }
    }

    // ---- one-time: LDS transposed-packed small matrices
    for (int e = t; e < 256 * 64; e += 512) {          // D21 [256][64]
        int r = e >> 6, c = e & 63;
        D21T[((c >> 2) * 256 + r) * 4 + (c & 3)] = (half_t)D21_g[e];
    }
    for (int e = t; e < 256 * 64; e += 512) {          // B [256][64]
        int r = e >> 6, c = e & 63;
        BT[((c >> 2) * 256 + r) * 4 + (c & 3)] = (half_t)B_g[e];
    }
    for (int e = t; e < 64 * 256; e += 512) {          // C [64][256]
        int r = e >> 8, c = e & 255;
        CT[((c >> 2) * 64 + r) * 4 + (c & 3)] = (half_t)C_g[e];
    }
    for (int e = t; e < 64 * 256; e += 512) {          // D12 [64][256]
        int r = e >> 8, c = e & 255;
        D12T[((c >> 2) * 64 + r) * 4 + (c & 3)] = (half_t)D12_g[e];
    }
    for (int e = t; e < 64 * 64; e += 512) {           // D [64][64]
        int r = e >> 6, c = e & 63;
        DT[((c >> 2) * 64 + r) * 4 + (c & 3)] = (half_t)D_g[e];
    }
    // initial state + d_0
    if (t < 256) x_h[t] = (half_t)x0_g[b * 256 + t];
    if (t >= 320 && t < 384) d_h[t - 320] = (half_t)d_g[(b * NSTEP) * 64 + (t - 320)];
    __syncthreads();

    const float* dpre = d_g + (b * NSTEP + 1) * 64 + (t - 320); // wave 5 prefetch ptr
    const int out_e_base = b * (NSTEP * 64);
    const int out_x_base = 256 * NSTEP * 64 + b * 256;          // 33554432 + ...
    const int out_w_base = 256 * NSTEP * 64 + 256 * 256 + b * 256;

    int cur = 0; // d ring slot for d_k (== k & 1)
    for (int k = 0; k <= NSTEP; ++k) {
        const bool live = (k < NSTEP);

        // prefetch d_{k+1} (wave 5)
        float dpf = 0.0f;
        if (k < NSTEP - 1 && t >= 320 && t < 384) dpf = *dpre;

        // ---- R1: w_pre partial (C2·x + D21·d) and A·x partial
        float aC0 = 0.f, aC1 = 0.f, aA0 = 0.f, aA1 = 0.f;
        if (live) {
            const half_t* xs = x_h + (g << 7);
#pragma unroll
            for (int cc = 0; cc < 16; ++cc) {
                F4H xv; xv.f = *(const float4*)(xs + cc * 8);
                aC0 = fdot2(c2r[4*cc+0], xv.h[0], aC0);
                aA0 = fdot2(ar [4*cc+0], xv.h[0], aA0);
                aC1 = fdot2(c2r[4*cc+1], xv.h[1], aC1);
                aA1 = fdot2(ar [4*cc+1], xv.h[1], aA1);
                aC0 = fdot2(c2r[4*cc+2], xv.h[2], aC0);
                aA0 = fdot2(ar [4*cc+2], xv.h[2], aA0);
                aC1 = fdot2(c2r[4*cc+3], xv.h[3], aC1);
                aA1 = fdot2(ar [4*cc+3], xv.h[3], aA1);
            }
#pragma unroll
            for (int q = 0; q < 8; ++q) {
                int j4 = (g << 3) + q;
                F2H m;  m.f  = *(const float2*)(D21T + (j4 * 256 + i) * 4);
                F2H dv; dv.f = *(const float2*)(d_h + cur * 64 + (j4 << 2));
                aC0 = fdot2(m.h[0], dv.h[0], aC0);
                aC1 = fdot2(m.h[1], dv.h[1], aC1);
            }
            red_a[t] = aC0 + aC1;
        }

        // ---- E phase for step k-1: e = C·x_k + D12·w_{k-1} + D·d_{k-1}
        if (k > 0) {
            float aE0 = 0.f, aE1 = 0.f;
#pragma unroll
            for (int q = 0; q < 8; ++q) {
                int j4 = (sl << 3) + q;
                F2H m;  m.f  = *(const float2*)(CT + (j4 * 64 + ie) * 4);
                F2H xv; xv.f = *(const float2*)(x_h + (j4 << 2));
                aE0 = fdot2(m.h[0], xv.h[0], aE0);
                aE1 = fdot2(m.h[1], xv.h[1], aE1);
            }
#pragma unroll
            for (int q = 0; q < 8; ++q) {
                int j4 = (sl << 3) + q;
                F2H m;  m.f  = *(const float2*)(D12T + (j4 * 64 + ie) * 4);
                F2H wv; wv.f = *(const float2*)(w_h + (j4 << 2));
                aE0 = fdot2(m.h[0], wv.h[0], aE0);
                aE1 = fdot2(m.h[1], wv.h[1], aE1);
            }
#pragma unroll
            for (int q = 0; q < 2; ++q) {
                int j4 = (sl << 1) + q;
                F2H m;  m.f  = *(const float2*)(DT + (j4 * 64 + ie) * 4);
                F2H dv; dv.f = *(const float2*)(d_h + (cur ^ 1) * 64 + (j4 << 2));
                aE0 = fdot2(m.h[0], dv.h[0], aE0);
                aE1 = fdot2(m.h[1], dv.h[1], aE1);
            }
            red_e[t] = aE0 + aE1;
        }
        __syncthreads(); // A

        // ---- R2: tanh+w (waves 0-3) | e-reduce+store (wave 4) | d_h fill (wave 5)
        if (t < 256) {
            if (live) {
                float p = red_a[t] + red_a[t + 256];
                float wv = tanh_fast(p);
                w_h[t] = (half_t)wv;
                if (k == NSTEP - 1) out[out_w_base + t] = wv;
            }
        } else if (t < 320) {
            if (k > 0) {
                float ev = red_e[ie] + red_e[64 + ie] + red_e[128 + ie] + red_e[192 + ie]
                         + red_e[256 + ie] + red_e[320 + ie] + red_e[384 + ie] + red_e[448 + ie];
                out[out_e_base + (k - 1) * 64 + ie] = ev;
            }
        } else if (t < 384) {
            if (k < NSTEP - 1) d_h[(cur ^ 1) * 64 + (t - 320)] = (half_t)dpf;
        }
        __syncthreads(); // B

        // ---- R3: x' partial (A·x done) + B2·w + B·d
        if (live) {
            float aX0 = aA0, aX1 = aA1;
            const half_t* wsl = w_h + (g << 7);
#pragma unroll
            for (int cc = 0; cc < 16; ++cc) {
                F4H wv; wv.f = *(const float4*)(wsl + cc * 8);
                aX0 = fdot2(b2r[4*cc+0], wv.h[0], aX0);
                aX1 = fdot2(b2r[4*cc+1], wv.h[1], aX1);
                aX0 = fdot2(b2r[4*cc+2], wv.h[2], aX0);
                aX1 = fdot2(b2r[4*cc+3], wv.h[3], aX1);
            }
#pragma unroll
            for (int q = 0; q < 8; ++q) {
                int j4 = (g << 3) + q;
                F2H m;  m.f  = *(const float2*)(BT + (j4 * 256 + i) * 4);
                F2H dv; dv.f = *(const float2*)(d_h + cur * 64 + (j4 << 2));
                aX0 = fdot2(m.h[0], dv.h[0], aX0);
                aX1 = fdot2(m.h[1], dv.h[1], aX1);
            }
            red_a[t] = aX0 + aX1;
        }
        __syncthreads(); // C

        // ---- R4: x update
        if (live && t < 256) {
            float xv = red_a[t] + red_a[t + 256];
            x_h[t] = (half_t)xv;
            if (k == NSTEP - 1) out[out_x_base + t] = xv;
        }
        dpre += 64;
        cur ^= 1;
        __syncthreads(); // D
    }
}

extern "C" void kernel_launch(void* const* d_in, const int* in_sizes, int n_in,
                              void* d_out, int out_size, void* d_ws, size_t ws_size,
                              hipStream_t stream) {
    (void)in_sizes; (void)n_in; (void)out_size; (void)d_ws; (void)ws_size;
    const float* d_  = (const float*)d_in[0];
    const float* x0  = (const float*)d_in[1];
    const float* A   = (const float*)d_in[2];
    const float* B   = (const float*)d_in[3];
    const float* B2  = (const float*)d_in[4];
    const float* C   = (const float*)d_in[5];
    const float* D   = (const float*)d_in[6];
    const float* D12 = (const float*)d_in[7];
    const float* C2  = (const float*)d_in[8];
    const float* D21 = (const float*)d_in[9];
    float* out = (float*)d_out;

    hipFuncSetAttribute((const void*)lure_kernel,
                        hipFuncAttributeMaxDynamicSharedMemorySize, LDS_TOTAL);
    hipLaunchKernelGGL(lure_kernel, dim3(256), dim3(512), LDS_TOTAL, stream,
                       d_, x0, A, B, B2, C, D, D12, C2, D21, out);
}

// Round 2
// 39206.406 us; speedup vs baseline: 1.0244x; 1.0244x over previous
//
#include <hip/hip_runtime.h>

// LureSystem recurrence, MI355X.
// Strategy: batch-parallel (256 blocks, 1 batch element each, 1 block/CU),
// serial loop over 2048 steps inside the kernel. Big matrices (C2,A,B2) in
// per-thread registers as packed f16 (v_dot2_f32_f16, 2 MAC/cyc/lane);
// small matrices (D21,B,C,D12,D) in LDS transposed-packed; state x,w as f16
// in LDS; fp32 accumulation; e computed fully inline (no workspace).
//
// R1 fix: amdgpu_waves_per_eu(2,2) pins the allocator to the 256-VGPR tier.
// Without the max bound, the compiler targeted 4 waves/EU (128 VGPRs) and
// spilled the 192 weight registers -> 27 GB scratch traffic -> 40 ms.

#define NSTEP 2048

typedef _Float16 half_t;
typedef _Float16 half2_t __attribute__((ext_vector_type(2)));

__device__ __forceinline__ float fdot2(half2_t a, half2_t b, float c) {
    return __builtin_amdgcn_fdot2(a, b, c, false);
}

union F4H { float4 f; half2_t h[4]; };
union F2H { float2 f; half2_t h[2]; };

__device__ __forceinline__ float tanh_fast(float p) {
    float ex = __expf(2.0f * p);
    return 1.0f - 2.0f / (ex + 1.0f);
}

// LDS layout (bytes):
//      0: D21T4  [16 j4][256 i][4h]  32768
//  32768: BT4    [16 j4][256 i][4h]  32768
//  65536: CT4    [64 j4][ 64 i][4h]  32768
//  98304: D12T4  [64 j4][ 64 i][4h]  32768
// 131072: DT4    [16 j4][ 64 i][4h]   8192
// 139264: x_h    [256] half            512
// 139776: w_h    [256] half            512
// 140288: d_h    [2][64] half          256
// 140544: red_a  [512] float          2048
// 142592: red_e  [512] float          2048
// total 144640 B
#define LDS_TOTAL 144640

__global__
__attribute__((amdgpu_flat_work_group_size(512, 512)))
__attribute__((amdgpu_waves_per_eu(2, 2)))
void lure_kernel(const float* __restrict__ d_g, const float* __restrict__ x0_g,
                 const float* __restrict__ A_g, const float* __restrict__ B_g,
                 const float* __restrict__ B2_g, const float* __restrict__ C_g,
                 const float* __restrict__ D_g, const float* __restrict__ D12_g,
                 const float* __restrict__ C2_g, const float* __restrict__ D21_g,
                 float* __restrict__ out)
{
    extern __shared__ char smem[];
    half_t* D21T = (half_t*)(smem + 0);
    half_t* BT   = (half_t*)(smem + 32768);
    half_t* CT   = (half_t*)(smem + 65536);
    half_t* D12T = (half_t*)(smem + 98304);
    half_t* DT   = (half_t*)(smem + 131072);
    half_t* x_h  = (half_t*)(smem + 139264);
    half_t* w_h  = (half_t*)(smem + 139776);
    half_t* d_h  = (half_t*)(smem + 140288);
    float*  red_a= (float*)(smem + 140544);
    float*  red_e= (float*)(smem + 142592);

    const int t = threadIdx.x;
    const int b = blockIdx.x;
    const int i = t & 255;    // output row for w/x phases
    const int g = t >> 8;     // K-half (0: j 0..127 / d 0..31, 1: rest)
    const int ie = t & 63;    // output row for e phase
    const int sl = t >> 6;    // e-phase K slice (8 slices)

    // ---- one-time: register-resident slices of C2, A, B2 (row i, half g)
    // (three separate loops to keep the one-time pressure spike low)
    half2_t c2r[64], ar[64], b2r[64];
    {
        const float4* c2p = (const float4*)(C2_g + i * 256 + g * 128);
#pragma unroll
        for (int u = 0; u < 32; ++u) {
            float4 v = c2p[u];
            c2r[2*u]   = half2_t{(half_t)v.x, (half_t)v.y};
            c2r[2*u+1] = half2_t{(half_t)v.z, (half_t)v.w};
        }
        const float4* ap = (const float4*)(A_g + i * 256 + g * 128);
#pragma unroll
        for (int u = 0; u < 32; ++u) {
            float4 v = ap[u];
            ar[2*u]    = half2_t{(half_t)v.x, (half_t)v.y};
            ar[2*u+1]  = half2_t{(half_t)v.z, (half_t)v.w};
        }
        const float4* b2p = (const float4*)(B2_g + i * 256 + g * 128);
#pragma unroll
        for (int u = 0; u < 32; ++u) {
            float4 v = b2p[u];
            b2r[2*u]   = half2_t{(half_t)v.x, (half_t)v.y};
            b2r[2*u+1] = half2_t{(half_t)v.z, (half_t)v.w};
        }
    }

    // ---- one-time: LDS transposed-packed small matrices
    for (int e = t; e < 256 * 64; e += 512) {          // D21 [256][64]
        int r = e >> 6, c = e & 63;
        D21T[((c >> 2) * 256 + r) * 4 + (c & 3)] = (half_t)D21_g[e];
    }
    for (int e = t; e < 256 * 64; e += 512) {          // B [256][64]
        int r = e >> 6, c = e & 63;
        BT[((c >> 2) * 256 + r) * 4 + (c & 3)] = (half_t)B_g[e];
    }
    for (int e = t; e < 64 * 256; e += 512) {          // C [64][256]
        int r = e >> 8, c = e & 255;
        CT[((c >> 2) * 64 + r) * 4 + (c & 3)] = (half_t)C_g[e];
    }
    for (int e = t; e < 64 * 256; e += 512) {          // D12 [64][256]
        int r = e >> 8, c = e & 255;
        D12T[((c >> 2) * 64 + r) * 4 + (c & 3)] = (half_t)D12_g[e];
    }
    for (int e = t; e < 64 * 64; e += 512) {           // D [64][64]
        int r = e >> 6, c = e & 63;
        DT[((c >> 2) * 64 + r) * 4 + (c & 3)] = (half_t)D_g[e];
    }
    // initial state + d_0
    if (t < 256) x_h[t] = (half_t)x0_g[b * 256 + t];
    if (t >= 320 && t < 384) d_h[t - 320] = (half_t)d_g[(b * NSTEP) * 64 + (t - 320)];
    __syncthreads();

    const float* dpre = d_g + (b * NSTEP + 1) * 64 + (t - 320); // wave 5 prefetch ptr
    const int out_e_base = b * (NSTEP * 64);
    const int out_x_base = 256 * NSTEP * 64 + b * 256;          // 33554432 + ...
    const int out_w_base = 256 * NSTEP * 64 + 256 * 256 + b * 256;

    int cur = 0; // d ring slot for d_k (== k & 1)
    for (int k = 0; k <= NSTEP; ++k) {
        const bool live = (k < NSTEP);

        // prefetch d_{k+1} (wave 5)
        float dpf = 0.0f;
        if (k < NSTEP - 1 && t >= 320 && t < 384) dpf = *dpre;

        // ---- R1: w_pre partial (C2·x + D21·d) and A·x partial
        float aC0 = 0.f, aC1 = 0.f, aA0 = 0.f, aA1 = 0.f;
        if (live) {
            const half_t* xs = x_h + (g << 7);
#pragma unroll
            for (int cc = 0; cc < 16; ++cc) {
                F4H xv; xv.f = *(const float4*)(xs + cc * 8);
                aC0 = fdot2(c2r[4*cc+0], xv.h[0], aC0);
                aA0 = fdot2(ar [4*cc+0], xv.h[0], aA0);
                aC1 = fdot2(c2r[4*cc+1], xv.h[1], aC1);
                aA1 = fdot2(ar [4*cc+1], xv.h[1], aA1);
                aC0 = fdot2(c2r[4*cc+2], xv.h[2], aC0);
                aA0 = fdot2(ar [4*cc+2], xv.h[2], aA0);
                aC1 = fdot2(c2r[4*cc+3], xv.h[3], aC1);
                aA1 = fdot2(ar [4*cc+3], xv.h[3], aA1);
            }
#pragma unroll
            for (int q = 0; q < 8; ++q) {
                int j4 = (g << 3) + q;
                F2H m;  m.f  = *(const float2*)(D21T + (j4 * 256 + i) * 4);
                F2H dv; dv.f = *(const float2*)(d_h + cur * 64 + (j4 << 2));
                aC0 = fdot2(m.h[0], dv.h[0], aC0);
                aC1 = fdot2(m.h[1], dv.h[1], aC1);
            }
            red_a[t] = aC0 + aC1;
        }

        // ---- E phase for step k-1: e = C·x_k + D12·w_{k-1} + D·d_{k-1}
        if (k > 0) {
            float aE0 = 0.f, aE1 = 0.f;
#pragma unroll
            for (int q = 0; q < 8; ++q) {
                int j4 = (sl << 3) + q;
                F2H m;  m.f  = *(const float2*)(CT + (j4 * 64 + ie) * 4);
                F2H xv; xv.f = *(const float2*)(x_h + (j4 << 2));
                aE0 = fdot2(m.h[0], xv.h[0], aE0);
                aE1 = fdot2(m.h[1], xv.h[1], aE1);
            }
#pragma unroll
            for (int q = 0; q < 8; ++q) {
                int j4 = (sl << 3) + q;
                F2H m;  m.f  = *(const float2*)(D12T + (j4 * 64 + ie) * 4);
                F2H wv; wv.f = *(const float2*)(w_h + (j4 << 2));
                aE0 = fdot2(m.h[0], wv.h[0], aE0);
                aE1 = fdot2(m.h[1], wv.h[1], aE1);
            }
#pragma unroll
            for (int q = 0; q < 2; ++q) {
                int j4 = (sl << 1) + q;
                F2H m;  m.f  = *(const float2*)(DT + (j4 * 64 + ie) * 4);
                F2H dv; dv.f = *(const float2*)(d_h + (cur ^ 1) * 64 + (j4 << 2));
                aE0 = fdot2(m.h[0], dv.h[0], aE0);
                aE1 = fdot2(m.h[1], dv.h[1], aE1);
            }
            red_e[t] = aE0 + aE1;
        }
        __syncthreads(); // A

        // ---- R2: tanh+w (waves 0-3) | e-reduce+store (wave 4) | d_h fill (wave 5)
        if (t < 256) {
            if (live) {
                float p = red_a[t] + red_a[t + 256];
                float wv = tanh_fast(p);
                w_h[t] = (half_t)wv;
                if (k == NSTEP - 1) out[out_w_base + t] = wv;
            }
        } else if (t < 320) {
            if (k > 0) {
                float ev = red_e[ie] + red_e[64 + ie] + red_e[128 + ie] + red_e[192 + ie]
                         + red_e[256 + ie] + red_e[320 + ie] + red_e[384 + ie] + red_e[448 + ie];
                out[out_e_base + (k - 1) * 64 + ie] = ev;
            }
        } else if (t < 384) {
            if (k < NSTEP - 1) d_h[(cur ^ 1) * 64 + (t - 320)] = (half_t)dpf;
        }
        __syncthreads(); // B

        // ---- R3: x' partial (A·x done) + B2·w + B·d
        if (live) {
            float aX0 = aA0, aX1 = aA1;
            const half_t* wsl = w_h + (g << 7);
#pragma unroll
            for (int cc = 0; cc < 16; ++cc) {
                F4H wv; wv.f = *(const float4*)(wsl + cc * 8);
                aX0 = fdot2(b2r[4*cc+0], wv.h[0], aX0);
                aX1 = fdot2(b2r[4*cc+1], wv.h[1], aX1);
                aX0 = fdot2(b2r[4*cc+2], wv.h[2], aX0);
                aX1 = fdot2(b2r[4*cc+3], wv.h[3], aX1);
            }
#pragma unroll
            for (int q = 0; q < 8; ++q) {
                int j4 = (g << 3) + q;
                F2H m;  m.f  = *(const float2*)(BT + (j4 * 256 + i) * 4);
                F2H dv; dv.f = *(const float2*)(d_h + cur * 64 + (j4 << 2));
                aX0 = fdot2(m.h[0], dv.h[0], aX0);
                aX1 = fdot2(m.h[1], dv.h[1], aX1);
            }
            red_a[t] = aX0 + aX1;
        }
        __syncthreads(); // C

        // ---- R4: x update
        if (live && t < 256) {
            float xv = red_a[t] + red_a[t + 256];
            x_h[t] = (half_t)xv;
            if (k == NSTEP - 1) out[out_x_base + t] = xv;
        }
        dpre += 64;
        cur ^= 1;
        __syncthreads(); // D
    }
}

extern "C" void kernel_launch(void* const* d_in, const int* in_sizes, int n_in,
                              void* d_out, int out_size, void* d_ws, size_t ws_size,
                              hipStream_t stream) {
    (void)in_sizes; (void)n_in; (void)out_size; (void)d_ws; (void)ws_size;
    const float* d_  = (const float*)d_in[0];
    const float* x0  = (const float*)d_in[1];
    const float* A   = (const float*)d_in[2];
    const float* B   = (const float*)d_in[3];
    const float* B2  = (const float*)d_in[4];
    const float* C   = (const float*)d_in[5];
    const float* D   = (const float*)d_in[6];
    const float* D12 = (const float*)d_in[7];
    const float* C2  = (const float*)d_in[8];
    const float* D21 = (const float*)d_in[9];
    float* out = (float*)d_out;

    hipFuncSetAttribute((const void*)lure_kernel,
                        hipFuncAttributeMaxDynamicSharedMemorySize, LDS_TOTAL);
    hipLaunchKernelGGL(lure_kernel, dim3(256), dim3(512), LDS_TOTAL, stream,
                       d_, x0, A, B, B2, C, D, D12, C2, D21, out);
}